// Round 5
// baseline (195.275 us; speedup 1.0000x reference)
//
#include <hip/hip_runtime.h>
#include <hip/hip_bf16.h>

#define SS 4
#define CC 128
#define WELEM 18432   // per-(s,c) W chunk, bf16 elems: 16384 main [n][jl] + 2048 tail (B-frag)
#define NK3 23
#define NK2 5
#define NK1 2
#define DLP 72        // Dl row stride (ushorts); 144 B = 16B-aligned rows

typedef unsigned int uint;
typedef unsigned short ushort;
typedef __attribute__((ext_vector_type(8))) short bf16x8;
typedef __attribute__((ext_vector_type(4))) float f32x4;

__device__ __forceinline__ float bflo(uint u){ return __uint_as_float(u << 16); }
__device__ __forceinline__ float bfhi(uint u){ return __uint_as_float(u & 0xffff0000u); }
__device__ __forceinline__ ushort f2bf(float f) {
  uint u = __float_as_uint(f);
  return (ushort)((u + 0x7fffu + ((u >> 16) & 1u)) >> 16);
}
__device__ __forceinline__ uint pk2(float a, float b) {
  __hip_bfloat162 h = __float22bfloat162_rn(make_float2(a, b));  // v_cvt_pk_bf16_f32
  return *(uint*)&h;
}

// ============ pre_kernel: fold3 (blocks 0..511) + fold21 (512..1023) + sort (1024) ============
__global__ __launch_bounds__(256) void pre_kernel(
    const float* __restrict__ u3_0, const float* __restrict__ u3_1,
    const float* __restrict__ w3,
    const float* __restrict__ u2_0, const float* __restrict__ u2_1,
    const float* __restrict__ u1_0, const float* __restrict__ u1_1,
    const float* __restrict__ w2,  const float* __restrict__ w1,
    const int* __restrict__ sp, ushort* __restrict__ W,
    int* __restrict__ sorted, int* __restrict__ seg) {
  __shared__ float smem[5888 + NK3 * 64];
  int bx = blockIdx.x;
  int tid = threadIdx.x;

  if (bx < 512) {
    // ---- fold3: W main, linear layout [s][c][n=o*16+i][jl], coalesced stores ----
    float* u3s = smem;            // 5888 floats
    float* w3s = smem + 5888;     // 23*64 floats
    int ch = bx & 1, i = (bx >> 1) & 15, o = (bx >> 5) & 3, s = bx >> 7;
    int g = (o > 0) ? 1 : 0, og = g ? (o - 1) : 0;
    const float* u3 = g ? u3_1 : u3_0;

    const float4* u3p = (const float4*)(u3 + (size_t)(og * 16 + i) * 5888);
    for (int d = tid; d < 1472; d += 256) {
      float4 v = u3p[d];
      u3s[4 * d] = v.x; u3s[4 * d + 1] = v.y; u3s[4 * d + 2] = v.z; u3s[4 * d + 3] = v.w;
    }
    for (int t = tid; t < NK3 * 64; t += 256) {
      int k = t >> 6, cp = t & 63;
      w3s[t] = w3[((size_t)(g * SS + s) * NK3 + k) * CC + ch * 64 + cp];
    }
    __syncthreads();

    float acc[64];
    #pragma unroll
    for (int q = 0; q < 64; q++) acc[q] = 0.f;
    int jl = tid;
    for (int k = 0; k < NK3; k++) {
      float u3v = u3s[jl * NK3 + k];
      const float4* wp = (const float4*)&w3s[k * 64];
      #pragma unroll
      for (int cq = 0; cq < 16; cq++) {
        float4 wv = wp[cq];
        acc[cq * 4 + 0] = fmaf(u3v, wv.x, acc[cq * 4 + 0]);
        acc[cq * 4 + 1] = fmaf(u3v, wv.y, acc[cq * 4 + 1]);
        acc[cq * 4 + 2] = fmaf(u3v, wv.z, acc[cq * 4 + 2]);
        acc[cq * 4 + 3] = fmaf(u3v, wv.w, acc[cq * 4 + 3]);
      }
    }
    int n = o * 16 + i;
    #pragma unroll
    for (int cp = 0; cp < 64; cp++) {
      W[(size_t)(s * CC + ch * 64 + cp) * WELEM + n * 256 + jl] = f2bf(acc[cp]);
    }
  } else if (bx < 1024) {
    // ---- fold21: W tail (k=256..287), stored directly in B-frag layout ----
    int b2 = bx - 512;
    int s = b2 >> 7, c = b2 & 127;
    int n = tid >> 2, lq = tid & 3;
    int o = n >> 4, i = n & 15;
    int g = (o > 0) ? 1 : 0, og = g ? (o - 1) : 0;
    const float* u2 = g ? u2_1 : u2_0;
    const float* u1 = g ? u1_1 : u1_0;

    float vals[8];
    #pragma unroll
    for (int t = 0; t < 8; t++) {
      int k = 256 + lq * 8 + t;
      float v = 0.f;
      if (k < 272) {
        int j = k - 256;
        #pragma unroll
        for (int k2 = 0; k2 < NK2; k2++)
          v = fmaf(u2[((size_t)(og * 16 + i) * 16 + j) * NK2 + k2],
                   w2[((size_t)(g * SS + s) * NK2 + k2) * CC + c], v);
      } else if (k == 272) {
        #pragma unroll
        for (int k2 = 0; k2 < NK1; k2++)
          v = fmaf(u1[(size_t)(og * 16 + i) * NK1 + k2],
                   w1[((size_t)(g * SS + s) * NK1 + k2) * CC + c], v);
      }
      vals[t] = v;
    }
    uint4 pk;
    pk.x = pk2(vals[0], vals[1]); pk.y = pk2(vals[2], vals[3]);
    pk.z = pk2(vals[4], vals[5]); pk.w = pk2(vals[6], vals[7]);
    size_t base = (size_t)(s * CC + c) * WELEM;
    size_t off = 16384 + ((size_t)o * 64 + lq * 16 + i) * 8;
    *(uint4*)(W + base + off) = pk;
  } else {
    // ---- sort nodes by species ----
    __shared__ int cnt[SS];
    __shared__ int basep[SS + 1];
    if (tid < SS) cnt[tid] = 0;
    __syncthreads();
    int mysp[4], mypos[4];
    #pragma unroll
    for (int q = 0; q < 4; q++) {
      int node = q * 256 + tid;
      int s = sp[node];
      mysp[q] = s;
      mypos[q] = atomicAdd(&cnt[s], 1);
    }
    __syncthreads();
    if (tid == 0) {
      basep[0] = 0;
      for (int q = 0; q < SS; q++) basep[q + 1] = basep[q] + cnt[q];
      for (int q = 0; q <= SS; q++) seg[q] = basep[q];
    }
    __syncthreads();
    #pragma unroll
    for (int q = 0; q < 4; q++)
      sorted[basep[mysp[q]] + mypos[q]] = q * 256 + tid;
  }
}

// ============ corr_kernel: MFMA symmetric contraction ============
// grid 1024 = h(2) x s(4) x c(128); 4 waves; wave w owns rows [w*16,w*16+16) of
// each 64-node slab; block h handles slabs h, h+2, h+4, ... of its (s,c) segment.
// A built in registers from per-lane global x row loads (prefetched); B: kt0..2
// reg-cached, kt3..8 in LDS. Epilogue via per-wave bf16 LDS transpose (no shfl).
__global__ __launch_bounds__(256, 4) void corr_kernel(
    const float* __restrict__ xg, const ushort* __restrict__ Wg,
    const int* __restrict__ sorted, const int* __restrict__ seg,
    float* __restrict__ y) {
  __shared__ uint4 Wl4[1536];                       // 24 KB: kt3..7 swizzled + kt8 tail
  __shared__ __align__(16) ushort Dl[4 * 16 * DLP]; // 9 KB, per-wave region
  int bx = blockIdx.x;
  int h = bx >> 9, s = (bx >> 7) & 3, c = bx & 127;
  int tid = threadIdx.x;
  int w = tid >> 6, lane = tid & 63;
  int lq = lane >> 4, ln = lane & 15;

  const uint4* wg = (const uint4*)(Wg + (size_t)(s * CC + c) * WELEM);

  // stage Wl: main kt3..7 (xor-swizzled) + tail kt8 (flat)
  for (int d = tid; d < 1280; d += 256) {
    int n = d / 20, j = d % 20;                // j = (kt-3)*4 + lqj
    int kt = 3 + (j >> 2), lqj = j & 3;
    int span = (kt - 3) * 4 + (n >> 4);
    int pos = (lqj * 16 + (n & 15)) ^ (kt & 7);
    Wl4[span * 64 + pos] = wg[n * 32 + 12 + j];
  }
  Wl4[1280 + tid] = wg[2048 + tid];
  // reg-cache B for kt0..2 (per-lane fragment, 12 uint4 = 48 VGPR)
  uint4 Bc[12];
  #pragma unroll
  for (int kt = 0; kt < 3; kt++)
    #pragma unroll
    for (int nt = 0; nt < 4; nt++)
      Bc[kt * 4 + nt] = wg[(nt * 16 + ln) * 32 + kt * 4 + lq];

  int s0 = seg[s], s1 = seg[s + 1];
  __syncthreads();  // Wl ready (the only barrier)

  int nslab = (s1 - s0 + 63) >> 6;
  int kslab = h;
  int sval = 0;
  float4 xc[4];
  if (kslab < nslab) {
    int row = s0 + kslab * 64 + w * 16 + ln;
    sval = sorted[min(row, s1 - 1)];
    const float4* xp = (const float4*)(xg + ((size_t)sval * CC + c) * 16);
    xc[0] = xp[0]; xc[1] = xp[1]; xc[2] = xp[2]; xc[3] = xp[3];
  }

  for (; kslab < nslab; kslab += 2) {
    // consume current x into registers
    float xv[16];
    #pragma unroll
    for (int q = 0; q < 4; q++) {
      xv[q * 4] = xc[q].x; xv[q * 4 + 1] = xc[q].y;
      xv[q * 4 + 2] = xc[q].z; xv[q * 4 + 3] = xc[q].w;
    }
    int svc = sval;
    int rowc = s0 + kslab * 64 + w * 16 + ln;
    // prefetch next slab (overlaps MFMA below)
    int kn = kslab + 2;
    if (kn < nslab) {
      int row = s0 + kn * 64 + w * 16 + ln;
      sval = sorted[min(row, s1 - 1)];
      const float4* xp = (const float4*)(xg + ((size_t)sval * CC + c) * 16);
      xc[0] = xp[0]; xc[1] = xp[1]; xc[2] = xp[2]; xc[3] = xp[3];
    }

    float xs8[8];
    #pragma unroll
    for (int t = 0; t < 8; t++) xs8[t] = (lq & 1) ? xv[8 + t] : xv[t];

    f32x4 acc[4];
    #pragma unroll
    for (int nt = 0; nt < 4; nt++) acc[nt] = (f32x4){0.f, 0.f, 0.f, 0.f};

    #pragma unroll
    for (int kt = 0; kt < 9; kt++) {
      uint4 av;
      if (kt < 8) {
        float xj = (lq & 2) ? xv[kt * 2 + 1] : xv[kt * 2];
        av.x = pk2(xj * xs8[0], xj * xs8[1]);
        av.y = pk2(xj * xs8[2], xj * xs8[3]);
        av.z = pk2(xj * xs8[4], xj * xs8[5]);
        av.w = pk2(xj * xs8[6], xj * xs8[7]);
      } else {
        av.x = pk2(xs8[0], xs8[1]);
        av.y = pk2(xs8[2], xs8[3]);
        av.z = pk2(xs8[4], xs8[5]);
        av.w = pk2(xs8[6], xs8[7]);
        if (lq == 2) av = make_uint4(0x3f80u, 0u, 0u, 0u);  // constant-1 column (k=272)
        if (lq == 3) av = make_uint4(0u, 0u, 0u, 0u);
      }
      bf16x8 a = *(bf16x8*)&av;
      #pragma unroll
      for (int nt = 0; nt < 4; nt++) {
        uint4 bv;
        if (kt < 3) {
          bv = Bc[kt * 4 + nt];
        } else if (kt < 8) {
          bv = Wl4[((kt - 3) * 4 + nt) * 64 + (lane ^ (kt & 7))];
        } else {
          bv = Wl4[1280 + nt * 64 + lane];
        }
        bf16x8 b = *(bf16x8*)&bv;
        acc[nt] = __builtin_amdgcn_mfma_f32_16x16x32_bf16(a, b, acc[nt], 0, 0, 0);
      }
    }

    // epilogue: per-wave LDS transpose of D (bf16), then lane (m=ln, o=lq)
    // reduces with its own xv (same row). C/D layout: row=lq*4+r, col=ln.
    #pragma unroll
    for (int nt = 0; nt < 4; nt++)
      #pragma unroll
      for (int r = 0; r < 4; r++)
        Dl[(w * 16 + lq * 4 + r) * DLP + nt * 16 + ln] = f2bf(acc[nt][r]);
    // same-wave write->read: compiler orders via lgkmcnt (LDS alias)
    const uint4* dp = (const uint4*)&Dl[(w * 16 + ln) * DLP + lq * 16];
    uint4 d0 = dp[0], d1 = dp[1];
    float r = 0.f;
    r = fmaf(bflo(d0.x), xv[0],  r); r = fmaf(bfhi(d0.x), xv[1],  r);
    r = fmaf(bflo(d0.y), xv[2],  r); r = fmaf(bfhi(d0.y), xv[3],  r);
    r = fmaf(bflo(d0.z), xv[4],  r); r = fmaf(bfhi(d0.z), xv[5],  r);
    r = fmaf(bflo(d0.w), xv[6],  r); r = fmaf(bfhi(d0.w), xv[7],  r);
    r = fmaf(bflo(d1.x), xv[8],  r); r = fmaf(bfhi(d1.x), xv[9],  r);
    r = fmaf(bflo(d1.y), xv[10], r); r = fmaf(bfhi(d1.y), xv[11], r);
    r = fmaf(bflo(d1.z), xv[12], r); r = fmaf(bfhi(d1.z), xv[13], r);
    r = fmaf(bflo(d1.w), xv[14], r); r = fmaf(bfhi(d1.w), xv[15], r);
    if (rowc < s1)
      y[((size_t)svc * CC + c) * 4 + lq] = r;
  }
}

// ============ lin_kernel: channel-mixing linear + pack ============
// grid 1024 (one node each) x 128 threads (n)
__global__ __launch_bounds__(128) void lin_kernel(
    const float* __restrict__ y, const float* __restrict__ w_lin,
    float* __restrict__ out) {
  int b = blockIdx.x;
  int n = threadIdx.x;
  const float4* yb4 = (const float4*)(y + (size_t)b * 512);
  float a0 = 0.f, a1 = 0.f, a2 = 0.f, a3 = 0.f;
  #pragma unroll 8
  for (int cc = 0; cc < CC; cc++) {
    float4 yv = yb4[cc];                        // uniform broadcast
    float wl0 = w_lin[(size_t)cc * CC + n];     // g=0
    float wl1 = w_lin[16384 + (size_t)cc * CC + n];
    a0 = fmaf(yv.x, wl0, a0);
    a1 = fmaf(yv.y, wl1, a1);
    a2 = fmaf(yv.z, wl1, a2);
    a3 = fmaf(yv.w, wl1, a3);
  }
  const float scale = 0.08838834764831845f;  // 1/sqrt(128)
  out[(size_t)b * 512 + n] = a0 * scale;
  out[(size_t)b * 512 + 128 + (size_t)n * 3 + 0] = a1 * scale;
  out[(size_t)b * 512 + 128 + (size_t)n * 3 + 1] = a2 * scale;
  out[(size_t)b * 512 + 128 + (size_t)n * 3 + 2] = a3 * scale;
}

extern "C" void kernel_launch(void* const* d_in, const int* in_sizes, int n_in,
                              void* d_out, int out_size, void* d_ws, size_t ws_size,
                              hipStream_t stream) {
  const float* node_feats = (const float*)d_in[0];
  const float* u3_0 = (const float*)d_in[1];
  const float* u3_1 = (const float*)d_in[2];
  const float* u2_0 = (const float*)d_in[3];
  const float* u2_1 = (const float*)d_in[4];
  const float* u1_0 = (const float*)d_in[5];
  const float* u1_1 = (const float*)d_in[6];
  const float* w3   = (const float*)d_in[7];
  const float* w2   = (const float*)d_in[8];
  const float* w1   = (const float*)d_in[9];
  const float* wlin = (const float*)d_in[10];
  const int* species = (const int*)d_in[11];
  float* out = (float*)d_out;

  char* ws = (char*)d_ws;
  ushort* W  = (ushort*)ws;                  // 512*18432*2 = 18,874,368 B
  float* yb  = (float*)(ws + 18874368);      //  2,097,152 B
  int* sorted = (int*)(ws + 20971520);       //      4,096 B
  int* seg    = (int*)(ws + 20975616);       //         32 B

  pre_kernel<<<1025, 256, 0, stream>>>(u3_0, u3_1, w3, u2_0, u2_1, u1_0, u1_1,
                                       w2, w1, species, W, sorted, seg);
  corr_kernel<<<1024, 256, 0, stream>>>(node_feats, W, sorted, seg, yb);
  lin_kernel<<<1024, 128, 0, stream>>>(yb, wlin, out);
}

// Round 6
// 171.730 us; speedup vs baseline: 1.1371x; 1.1371x over previous
//
#include <hip/hip_runtime.h>
#include <hip/hip_bf16.h>

#define SS 4
#define CC 128
#define WELEM 18432   // per-(s,c) W chunk, bf16 elems: 16384 main [n][jl] + 2048 tail (B-frag)
#define NK3 23
#define NK2 5
#define NK1 2
#define DLP 72        // Dl row stride (ushorts); 144 B = 16B-aligned rows

typedef unsigned int uint;
typedef unsigned short ushort;
typedef __attribute__((ext_vector_type(8))) short bf16x8;
typedef __attribute__((ext_vector_type(4))) float f32x4;

__device__ __forceinline__ float bflo(uint u){ return __uint_as_float(u << 16); }
__device__ __forceinline__ float bfhi(uint u){ return __uint_as_float(u & 0xffff0000u); }
__device__ __forceinline__ ushort f2bf(float f) {
  uint u = __float_as_uint(f);
  return (ushort)((u + 0x7fffu + ((u >> 16) & 1u)) >> 16);
}
__device__ __forceinline__ uint pk2(float a, float b) {
  __hip_bfloat162 h = __float22bfloat162_rn(make_float2(a, b));  // v_cvt_pk_bf16_f32
  return *(uint*)&h;
}

// ============ pre_kernel: fold3 (blocks 0..511) + fold21 (512..1023) + sort (1024) ============
__global__ __launch_bounds__(256) void pre_kernel(
    const float* __restrict__ u3_0, const float* __restrict__ u3_1,
    const float* __restrict__ w3,
    const float* __restrict__ u2_0, const float* __restrict__ u2_1,
    const float* __restrict__ u1_0, const float* __restrict__ u1_1,
    const float* __restrict__ w2,  const float* __restrict__ w1,
    const int* __restrict__ sp, ushort* __restrict__ W,
    int* __restrict__ sorted, int* __restrict__ seg) {
  __shared__ float smem[5888 + NK3 * 64];
  int bx = blockIdx.x;
  int tid = threadIdx.x;

  if (bx < 512) {
    // ---- fold3: W main, linear layout [s][c][n=o*16+i][jl], coalesced stores ----
    float* u3s = smem;            // 5888 floats
    float* w3s = smem + 5888;     // 23*64 floats
    int ch = bx & 1, i = (bx >> 1) & 15, o = (bx >> 5) & 3, s = bx >> 7;
    int g = (o > 0) ? 1 : 0, og = g ? (o - 1) : 0;
    const float* u3 = g ? u3_1 : u3_0;

    const float4* u3p = (const float4*)(u3 + (size_t)(og * 16 + i) * 5888);
    for (int d = tid; d < 1472; d += 256) {
      float4 v = u3p[d];
      u3s[4 * d] = v.x; u3s[4 * d + 1] = v.y; u3s[4 * d + 2] = v.z; u3s[4 * d + 3] = v.w;
    }
    for (int t = tid; t < NK3 * 64; t += 256) {
      int k = t >> 6, cp = t & 63;
      w3s[t] = w3[((size_t)(g * SS + s) * NK3 + k) * CC + ch * 64 + cp];
    }
    __syncthreads();

    float acc[64];
    #pragma unroll
    for (int q = 0; q < 64; q++) acc[q] = 0.f;
    int jl = tid;
    for (int k = 0; k < NK3; k++) {
      float u3v = u3s[jl * NK3 + k];
      const float4* wp = (const float4*)&w3s[k * 64];
      #pragma unroll
      for (int cq = 0; cq < 16; cq++) {
        float4 wv = wp[cq];
        acc[cq * 4 + 0] = fmaf(u3v, wv.x, acc[cq * 4 + 0]);
        acc[cq * 4 + 1] = fmaf(u3v, wv.y, acc[cq * 4 + 1]);
        acc[cq * 4 + 2] = fmaf(u3v, wv.z, acc[cq * 4 + 2]);
        acc[cq * 4 + 3] = fmaf(u3v, wv.w, acc[cq * 4 + 3]);
      }
    }
    int n = o * 16 + i;
    #pragma unroll
    for (int cp = 0; cp < 64; cp++) {
      W[(size_t)(s * CC + ch * 64 + cp) * WELEM + n * 256 + jl] = f2bf(acc[cp]);
    }
  } else if (bx < 1024) {
    // ---- fold21: W tail (k=256..287), stored directly in B-frag layout ----
    int b2 = bx - 512;
    int s = b2 >> 7, c = b2 & 127;
    int n = tid >> 2, lq = tid & 3;
    int o = n >> 4, i = n & 15;
    int g = (o > 0) ? 1 : 0, og = g ? (o - 1) : 0;
    const float* u2 = g ? u2_1 : u2_0;
    const float* u1 = g ? u1_1 : u1_0;

    float vals[8];
    #pragma unroll
    for (int t = 0; t < 8; t++) {
      int k = 256 + lq * 8 + t;
      float v = 0.f;
      if (k < 272) {
        int j = k - 256;
        #pragma unroll
        for (int k2 = 0; k2 < NK2; k2++)
          v = fmaf(u2[((size_t)(og * 16 + i) * 16 + j) * NK2 + k2],
                   w2[((size_t)(g * SS + s) * NK2 + k2) * CC + c], v);
      } else if (k == 272) {
        #pragma unroll
        for (int k2 = 0; k2 < NK1; k2++)
          v = fmaf(u1[(size_t)(og * 16 + i) * NK1 + k2],
                   w1[((size_t)(g * SS + s) * NK1 + k2) * CC + c], v);
      }
      vals[t] = v;
    }
    uint4 pk;
    pk.x = pk2(vals[0], vals[1]); pk.y = pk2(vals[2], vals[3]);
    pk.z = pk2(vals[4], vals[5]); pk.w = pk2(vals[6], vals[7]);
    size_t base = (size_t)(s * CC + c) * WELEM;
    size_t off = 16384 + ((size_t)o * 64 + lq * 16 + i) * 8;
    *(uint4*)(W + base + off) = pk;
  } else {
    // ---- sort nodes by species ----
    __shared__ int cnt[SS];
    __shared__ int basep[SS + 1];
    if (tid < SS) cnt[tid] = 0;
    __syncthreads();
    int mysp[4], mypos[4];
    #pragma unroll
    for (int q = 0; q < 4; q++) {
      int node = q * 256 + tid;
      int s = sp[node];
      mysp[q] = s;
      mypos[q] = atomicAdd(&cnt[s], 1);
    }
    __syncthreads();
    if (tid == 0) {
      basep[0] = 0;
      for (int q = 0; q < SS; q++) basep[q + 1] = basep[q] + cnt[q];
      for (int q = 0; q <= SS; q++) seg[q] = basep[q];
    }
    __syncthreads();
    #pragma unroll
    for (int q = 0; q < 4; q++)
      sorted[basep[mysp[q]] + mypos[q]] = q * 256 + tid;
  }
}

// ============ corr_kernel: MFMA symmetric contraction ============
// grid 1024 = h(2) x s(4) x c(128); 4 waves; wave w owns rows [w*16,w*16+16) of
// each 64-node slab; block h handles slabs h, h+2, h+4, ... of its (s,c) segment.
// A built in registers from per-lane global x row loads (prefetched); B: kt0..2
// reg-cached, kt3..8 in LDS. Epilogue via per-wave bf16 LDS transpose (no shfl).
// launch_bounds(256,3): VGPR cap ~170 — the (256,4) cap of 128 caused scratch
// spills (153 MB FETCH / 146 MB WRITE of spill traffic in round 5).
__global__ __launch_bounds__(256, 3) void corr_kernel(
    const float* __restrict__ xg, const ushort* __restrict__ Wg,
    const int* __restrict__ sorted, const int* __restrict__ seg,
    float* __restrict__ y) {
  __shared__ uint4 Wl4[1536];                       // 24 KB: kt3..7 swizzled + kt8 tail
  __shared__ __align__(16) ushort Dl[4 * 16 * DLP]; // 9 KB, per-wave region
  int bx = blockIdx.x;
  int h = bx >> 9, s = (bx >> 7) & 3, c = bx & 127;
  int tid = threadIdx.x;
  int w = tid >> 6, lane = tid & 63;
  int lq = lane >> 4, ln = lane & 15;

  const uint4* wg = (const uint4*)(Wg + (size_t)(s * CC + c) * WELEM);

  // stage Wl: main kt3..7 (xor-swizzled) + tail kt8 (flat)
  for (int d = tid; d < 1280; d += 256) {
    int n = d / 20, j = d % 20;                // j = (kt-3)*4 + lqj
    int kt = 3 + (j >> 2), lqj = j & 3;
    int span = (kt - 3) * 4 + (n >> 4);
    int pos = (lqj * 16 + (n & 15)) ^ (kt & 7);
    Wl4[span * 64 + pos] = wg[n * 32 + 12 + j];
  }
  Wl4[1280 + tid] = wg[2048 + tid];
  // reg-cache B for kt0..2 (per-lane fragment, 12 uint4 = 48 VGPR)
  uint4 Bc[12];
  #pragma unroll
  for (int kt = 0; kt < 3; kt++)
    #pragma unroll
    for (int nt = 0; nt < 4; nt++)
      Bc[kt * 4 + nt] = wg[(nt * 16 + ln) * 32 + kt * 4 + lq];

  int s0 = seg[s], s1 = seg[s + 1];
  __syncthreads();  // Wl ready (the only barrier)

  int nslab = (s1 - s0 + 63) >> 6;
  int kslab = h;
  int sval = 0;
  float4 xc[4];
  if (kslab < nslab) {
    int row = s0 + kslab * 64 + w * 16 + ln;
    sval = sorted[min(row, s1 - 1)];
    const float4* xp = (const float4*)(xg + ((size_t)sval * CC + c) * 16);
    xc[0] = xp[0]; xc[1] = xp[1]; xc[2] = xp[2]; xc[3] = xp[3];
  }

  for (; kslab < nslab; kslab += 2) {
    // consume current x into registers
    float xv[16];
    #pragma unroll
    for (int q = 0; q < 4; q++) {
      xv[q * 4] = xc[q].x; xv[q * 4 + 1] = xc[q].y;
      xv[q * 4 + 2] = xc[q].z; xv[q * 4 + 3] = xc[q].w;
    }
    int svc = sval;
    int rowc = s0 + kslab * 64 + w * 16 + ln;
    // prefetch next slab (overlaps MFMA below)
    int kn = kslab + 2;
    if (kn < nslab) {
      int row = s0 + kn * 64 + w * 16 + ln;
      sval = sorted[min(row, s1 - 1)];
      const float4* xp = (const float4*)(xg + ((size_t)sval * CC + c) * 16);
      xc[0] = xp[0]; xc[1] = xp[1]; xc[2] = xp[2]; xc[3] = xp[3];
    }

    float xs8[8];
    #pragma unroll
    for (int t = 0; t < 8; t++) xs8[t] = (lq & 1) ? xv[8 + t] : xv[t];

    f32x4 acc[4];
    #pragma unroll
    for (int nt = 0; nt < 4; nt++) acc[nt] = (f32x4){0.f, 0.f, 0.f, 0.f};

    #pragma unroll
    for (int kt = 0; kt < 9; kt++) {
      uint4 av;
      if (kt < 8) {
        float xj = (lq & 2) ? xv[kt * 2 + 1] : xv[kt * 2];
        av.x = pk2(xj * xs8[0], xj * xs8[1]);
        av.y = pk2(xj * xs8[2], xj * xs8[3]);
        av.z = pk2(xj * xs8[4], xj * xs8[5]);
        av.w = pk2(xj * xs8[6], xj * xs8[7]);
      } else {
        av.x = pk2(xs8[0], xs8[1]);
        av.y = pk2(xs8[2], xs8[3]);
        av.z = pk2(xs8[4], xs8[5]);
        av.w = pk2(xs8[6], xs8[7]);
        if (lq == 2) av = make_uint4(0x3f80u, 0u, 0u, 0u);  // constant-1 column (k=272)
        if (lq == 3) av = make_uint4(0u, 0u, 0u, 0u);
      }
      bf16x8 a = *(bf16x8*)&av;
      #pragma unroll
      for (int nt = 0; nt < 4; nt++) {
        uint4 bv;
        if (kt < 3) {
          bv = Bc[kt * 4 + nt];
        } else if (kt < 8) {
          bv = Wl4[((kt - 3) * 4 + nt) * 64 + (lane ^ (kt & 7))];
        } else {
          bv = Wl4[1280 + nt * 64 + lane];
        }
        bf16x8 b = *(bf16x8*)&bv;
        acc[nt] = __builtin_amdgcn_mfma_f32_16x16x32_bf16(a, b, acc[nt], 0, 0, 0);
      }
    }

    // epilogue: per-wave LDS transpose of D (bf16), then lane (m=ln, o=lq)
    // reduces with its own xv (same row). C/D layout: row=lq*4+r, col=ln.
    #pragma unroll
    for (int nt = 0; nt < 4; nt++)
      #pragma unroll
      for (int r = 0; r < 4; r++)
        Dl[(w * 16 + lq * 4 + r) * DLP + nt * 16 + ln] = f2bf(acc[nt][r]);
    // same-wave write->read: compiler orders via lgkmcnt (LDS alias)
    const uint4* dp = (const uint4*)&Dl[(w * 16 + ln) * DLP + lq * 16];
    uint4 d0 = dp[0], d1 = dp[1];
    float r = 0.f;
    r = fmaf(bflo(d0.x), xv[0],  r); r = fmaf(bfhi(d0.x), xv[1],  r);
    r = fmaf(bflo(d0.y), xv[2],  r); r = fmaf(bfhi(d0.y), xv[3],  r);
    r = fmaf(bflo(d0.z), xv[4],  r); r = fmaf(bfhi(d0.z), xv[5],  r);
    r = fmaf(bflo(d0.w), xv[6],  r); r = fmaf(bfhi(d0.w), xv[7],  r);
    r = fmaf(bflo(d1.x), xv[8],  r); r = fmaf(bfhi(d1.x), xv[9],  r);
    r = fmaf(bflo(d1.y), xv[10], r); r = fmaf(bfhi(d1.y), xv[11], r);
    r = fmaf(bflo(d1.z), xv[12], r); r = fmaf(bfhi(d1.z), xv[13], r);
    r = fmaf(bflo(d1.w), xv[14], r); r = fmaf(bfhi(d1.w), xv[15], r);
    if (rowc < s1)
      y[((size_t)svc * CC + c) * 4 + lq] = r;
  }
}

// ============ lin_kernel: channel-mixing linear + pack ============
// grid 1024 (one node each) x 128 threads (n)
__global__ __launch_bounds__(128) void lin_kernel(
    const float* __restrict__ y, const float* __restrict__ w_lin,
    float* __restrict__ out) {
  int b = blockIdx.x;
  int n = threadIdx.x;
  const float4* yb4 = (const float4*)(y + (size_t)b * 512);
  float a0 = 0.f, a1 = 0.f, a2 = 0.f, a3 = 0.f;
  #pragma unroll 8
  for (int cc = 0; cc < CC; cc++) {
    float4 yv = yb4[cc];                        // uniform broadcast
    float wl0 = w_lin[(size_t)cc * CC + n];     // g=0
    float wl1 = w_lin[16384 + (size_t)cc * CC + n];
    a0 = fmaf(yv.x, wl0, a0);
    a1 = fmaf(yv.y, wl1, a1);
    a2 = fmaf(yv.z, wl1, a2);
    a3 = fmaf(yv.w, wl1, a3);
  }
  const float scale = 0.08838834764831845f;  // 1/sqrt(128)
  out[(size_t)b * 512 + n] = a0 * scale;
  out[(size_t)b * 512 + 128 + (size_t)n * 3 + 0] = a1 * scale;
  out[(size_t)b * 512 + 128 + (size_t)n * 3 + 1] = a2 * scale;
  out[(size_t)b * 512 + 128 + (size_t)n * 3 + 2] = a3 * scale;
}

extern "C" void kernel_launch(void* const* d_in, const int* in_sizes, int n_in,
                              void* d_out, int out_size, void* d_ws, size_t ws_size,
                              hipStream_t stream) {
  const float* node_feats = (const float*)d_in[0];
  const float* u3_0 = (const float*)d_in[1];
  const float* u3_1 = (const float*)d_in[2];
  const float* u2_0 = (const float*)d_in[3];
  const float* u2_1 = (const float*)d_in[4];
  const float* u1_0 = (const float*)d_in[5];
  const float* u1_1 = (const float*)d_in[6];
  const float* w3   = (const float*)d_in[7];
  const float* w2   = (const float*)d_in[8];
  const float* w1   = (const float*)d_in[9];
  const float* wlin = (const float*)d_in[10];
  const int* species = (const int*)d_in[11];
  float* out = (float*)d_out;

  char* ws = (char*)d_ws;
  ushort* W  = (ushort*)ws;                  // 512*18432*2 = 18,874,368 B
  float* yb  = (float*)(ws + 18874368);      //  2,097,152 B
  int* sorted = (int*)(ws + 20971520);       //      4,096 B
  int* seg    = (int*)(ws + 20975616);       //         32 B

  pre_kernel<<<1025, 256, 0, stream>>>(u3_0, u3_1, w3, u2_0, u2_1, u1_0, u1_1,
                                       w2, w1, species, W, sorted, seg);
  corr_kernel<<<1024, 256, 0, stream>>>(node_feats, W, sorted, seg, yb);
  lin_kernel<<<1024, 128, 0, stream>>>(yb, wlin, out);
}

// Round 7
// 169.034 us; speedup vs baseline: 1.1552x; 1.0159x over previous
//
#include <hip/hip_runtime.h>
#include <hip/hip_bf16.h>

#define SS 4
#define CC 128
#define WELEM 18432   // per-(s,c) W chunk, bf16 elems: 16384 main [n][jl] + 2048 tail (B-frag)
#define NK3 23
#define NK2 5
#define NK1 2
#define DLP 72        // Dl row stride (ushorts); 144 B = 16B-aligned rows

typedef unsigned int uint;
typedef unsigned short ushort;
typedef __attribute__((ext_vector_type(8))) short bf16x8;
typedef __attribute__((ext_vector_type(4))) float f32x4;

__device__ __forceinline__ float bflo(uint u){ return __uint_as_float(u << 16); }
__device__ __forceinline__ float bfhi(uint u){ return __uint_as_float(u & 0xffff0000u); }
__device__ __forceinline__ ushort f2bf(float f) {
  uint u = __float_as_uint(f);
  return (ushort)((u + 0x7fffu + ((u >> 16) & 1u)) >> 16);
}
__device__ __forceinline__ uint pk2(float a, float b) {
  __hip_bfloat162 h = __float22bfloat162_rn(make_float2(a, b));  // v_cvt_pk_bf16_f32
  return *(uint*)&h;
}

// ============ pre_kernel: fold3 (blocks 0..511) + fold21 (512..1023) + sort (1024) ============
__global__ __launch_bounds__(256) void pre_kernel(
    const float* __restrict__ u3_0, const float* __restrict__ u3_1,
    const float* __restrict__ w3,
    const float* __restrict__ u2_0, const float* __restrict__ u2_1,
    const float* __restrict__ u1_0, const float* __restrict__ u1_1,
    const float* __restrict__ w2,  const float* __restrict__ w1,
    const int* __restrict__ sp, ushort* __restrict__ W,
    int* __restrict__ sorted, int* __restrict__ seg) {
  __shared__ float smem[5888 + NK3 * 64];
  int bx = blockIdx.x;
  int tid = threadIdx.x;

  if (bx < 512) {
    // ---- fold3: W main, linear layout [s][c][n=o*16+i][jl], coalesced stores ----
    float* u3s = smem;            // 5888 floats
    float* w3s = smem + 5888;     // 23*64 floats
    int ch = bx & 1, i = (bx >> 1) & 15, o = (bx >> 5) & 3, s = bx >> 7;
    int g = (o > 0) ? 1 : 0, og = g ? (o - 1) : 0;
    const float* u3 = g ? u3_1 : u3_0;

    const float4* u3p = (const float4*)(u3 + (size_t)(og * 16 + i) * 5888);
    for (int d = tid; d < 1472; d += 256) {
      float4 v = u3p[d];
      u3s[4 * d] = v.x; u3s[4 * d + 1] = v.y; u3s[4 * d + 2] = v.z; u3s[4 * d + 3] = v.w;
    }
    for (int t = tid; t < NK3 * 64; t += 256) {
      int k = t >> 6, cp = t & 63;
      w3s[t] = w3[((size_t)(g * SS + s) * NK3 + k) * CC + ch * 64 + cp];
    }
    __syncthreads();

    float acc[64];
    #pragma unroll
    for (int q = 0; q < 64; q++) acc[q] = 0.f;
    int jl = tid;
    for (int k = 0; k < NK3; k++) {
      float u3v = u3s[jl * NK3 + k];
      const float4* wp = (const float4*)&w3s[k * 64];
      #pragma unroll
      for (int cq = 0; cq < 16; cq++) {
        float4 wv = wp[cq];
        acc[cq * 4 + 0] = fmaf(u3v, wv.x, acc[cq * 4 + 0]);
        acc[cq * 4 + 1] = fmaf(u3v, wv.y, acc[cq * 4 + 1]);
        acc[cq * 4 + 2] = fmaf(u3v, wv.z, acc[cq * 4 + 2]);
        acc[cq * 4 + 3] = fmaf(u3v, wv.w, acc[cq * 4 + 3]);
      }
    }
    int n = o * 16 + i;
    #pragma unroll
    for (int cp = 0; cp < 64; cp++) {
      W[(size_t)(s * CC + ch * 64 + cp) * WELEM + n * 256 + jl] = f2bf(acc[cp]);
    }
  } else if (bx < 1024) {
    // ---- fold21: W tail (k=256..287), stored directly in B-frag layout ----
    int b2 = bx - 512;
    int s = b2 >> 7, c = b2 & 127;
    int n = tid >> 2, lq = tid & 3;
    int o = n >> 4, i = n & 15;
    int g = (o > 0) ? 1 : 0, og = g ? (o - 1) : 0;
    const float* u2 = g ? u2_1 : u2_0;
    const float* u1 = g ? u1_1 : u1_0;

    float vals[8];
    #pragma unroll
    for (int t = 0; t < 8; t++) {
      int k = 256 + lq * 8 + t;
      float v = 0.f;
      if (k < 272) {
        int j = k - 256;
        #pragma unroll
        for (int k2 = 0; k2 < NK2; k2++)
          v = fmaf(u2[((size_t)(og * 16 + i) * 16 + j) * NK2 + k2],
                   w2[((size_t)(g * SS + s) * NK2 + k2) * CC + c], v);
      } else if (k == 272) {
        #pragma unroll
        for (int k2 = 0; k2 < NK1; k2++)
          v = fmaf(u1[(size_t)(og * 16 + i) * NK1 + k2],
                   w1[((size_t)(g * SS + s) * NK1 + k2) * CC + c], v);
      }
      vals[t] = v;
    }
    uint4 pk;
    pk.x = pk2(vals[0], vals[1]); pk.y = pk2(vals[2], vals[3]);
    pk.z = pk2(vals[4], vals[5]); pk.w = pk2(vals[6], vals[7]);
    size_t base = (size_t)(s * CC + c) * WELEM;
    size_t off = 16384 + ((size_t)o * 64 + lq * 16 + i) * 8;
    *(uint4*)(W + base + off) = pk;
  } else {
    // ---- sort nodes by species ----
    __shared__ int cnt[SS];
    __shared__ int basep[SS + 1];
    if (tid < SS) cnt[tid] = 0;
    __syncthreads();
    int mysp[4], mypos[4];
    #pragma unroll
    for (int q = 0; q < 4; q++) {
      int node = q * 256 + tid;
      int s = sp[node];
      mysp[q] = s;
      mypos[q] = atomicAdd(&cnt[s], 1);
    }
    __syncthreads();
    if (tid == 0) {
      basep[0] = 0;
      for (int q = 0; q < SS; q++) basep[q + 1] = basep[q] + cnt[q];
      for (int q = 0; q <= SS; q++) seg[q] = basep[q];
    }
    __syncthreads();
    #pragma unroll
    for (int q = 0; q < 4; q++)
      sorted[basep[mysp[q]] + mypos[q]] = q * 256 + tid;
  }
}

// ============ corr_kernel: MFMA symmetric contraction ============
// grid 1024 = h(2) x s(4) x c(128); 4 waves; wave w owns rows [w*16,w*16+16) of
// each 64-node slab; block h handles slabs h, h+2, ... of its (s,c) segment.
// A built in registers from per-lane global x row loads (prefetched); ALL B
// fragments in LDS (no reg-cache — the 48-VGPR Bc array caused scratch spills
// in rounds 5/6: ~100-150 MB FETCH+WRITE of spill traffic each).
// Epilogue via per-wave bf16 LDS transpose (no shfl).
__global__ __launch_bounds__(256, 3) void corr_kernel(
    const float* __restrict__ xg, const ushort* __restrict__ Wg,
    const int* __restrict__ sorted, const int* __restrict__ seg,
    float* __restrict__ y) {
  __shared__ uint4 Wl4[2304];                       // 36 KB: kt0..7 swizzled + kt8 tail
  __shared__ __align__(16) ushort Dl[4 * 16 * DLP]; // 9 KB, per-wave region
  int bx = blockIdx.x;
  int h = bx >> 9, s = (bx >> 7) & 3, c = bx & 127;
  int tid = threadIdx.x;
  int w = tid >> 6, lane = tid & 63;
  int lq = lane >> 4, ln = lane & 15;

  const uint4* wg = (const uint4*)(Wg + (size_t)(s * CC + c) * WELEM);

  // stage Wl: main kt0..7 (xor-swizzled), coalesced global reads
  for (int d = tid; d < 2048; d += 256) {
    int n = d >> 5, j = d & 31;            // j = kt*4 + lqj
    int kt = j >> 2, lqj = j & 3;
    int span = kt * 4 + (n >> 4);
    int pos = (lqj * 16 + (n & 15)) ^ kt;
    Wl4[span * 64 + pos] = wg[d];
  }
  // tail kt8 (flat; already in B-frag order from fold21)
  Wl4[2048 + tid] = wg[2048 + tid];

  int s0 = seg[s], s1 = seg[s + 1];
  __syncthreads();  // Wl ready (the only barrier)

  int nslab = (s1 - s0 + 63) >> 6;
  int kslab = h;
  int sval = 0;
  float4 xc[4];
  if (kslab < nslab) {
    int row = s0 + kslab * 64 + w * 16 + ln;
    sval = sorted[min(row, s1 - 1)];
    const float4* xp = (const float4*)(xg + ((size_t)sval * CC + c) * 16);
    xc[0] = xp[0]; xc[1] = xp[1]; xc[2] = xp[2]; xc[3] = xp[3];
  }

  for (; kslab < nslab; kslab += 2) {
    // consume current x into registers
    float xv[16];
    #pragma unroll
    for (int q = 0; q < 4; q++) {
      xv[q * 4] = xc[q].x; xv[q * 4 + 1] = xc[q].y;
      xv[q * 4 + 2] = xc[q].z; xv[q * 4 + 3] = xc[q].w;
    }
    int svc = sval;
    int rowc = s0 + kslab * 64 + w * 16 + ln;
    // prefetch next slab (overlaps MFMA below)
    int kn = kslab + 2;
    if (kn < nslab) {
      int row = s0 + kn * 64 + w * 16 + ln;
      sval = sorted[min(row, s1 - 1)];
      const float4* xp = (const float4*)(xg + ((size_t)sval * CC + c) * 16);
      xc[0] = xp[0]; xc[1] = xp[1]; xc[2] = xp[2]; xc[3] = xp[3];
    }

    float xs8[8];
    #pragma unroll
    for (int t = 0; t < 8; t++) xs8[t] = (lq & 1) ? xv[8 + t] : xv[t];

    f32x4 acc[4];
    #pragma unroll
    for (int nt = 0; nt < 4; nt++) acc[nt] = (f32x4){0.f, 0.f, 0.f, 0.f};

    #pragma unroll
    for (int kt = 0; kt < 9; kt++) {
      uint4 av;
      if (kt < 8) {
        float xj = (lq & 2) ? xv[kt * 2 + 1] : xv[kt * 2];
        av.x = pk2(xj * xs8[0], xj * xs8[1]);
        av.y = pk2(xj * xs8[2], xj * xs8[3]);
        av.z = pk2(xj * xs8[4], xj * xs8[5]);
        av.w = pk2(xj * xs8[6], xj * xs8[7]);
      } else {
        av.x = pk2(xs8[0], xs8[1]);
        av.y = pk2(xs8[2], xs8[3]);
        av.z = pk2(xs8[4], xs8[5]);
        av.w = pk2(xs8[6], xs8[7]);
        if (lq == 2) av = make_uint4(0x3f80u, 0u, 0u, 0u);  // constant-1 column (k=272)
        if (lq == 3) av = make_uint4(0u, 0u, 0u, 0u);
      }
      bf16x8 a = *(bf16x8*)&av;
      #pragma unroll
      for (int nt = 0; nt < 4; nt++) {
        uint4 bv;
        if (kt < 8) {
          bv = Wl4[(kt * 4 + nt) * 64 + (lane ^ kt)];
        } else {
          bv = Wl4[2048 + nt * 64 + lane];
        }
        bf16x8 b = *(bf16x8*)&bv;
        acc[nt] = __builtin_amdgcn_mfma_f32_16x16x32_bf16(a, b, acc[nt], 0, 0, 0);
      }
    }

    // epilogue: per-wave LDS transpose of D (bf16), then lane (m=ln, o=lq)
    // reduces with its own xv (same row). C/D layout: row=lq*4+r, col=ln.
    #pragma unroll
    for (int nt = 0; nt < 4; nt++)
      #pragma unroll
      for (int r = 0; r < 4; r++)
        Dl[(w * 16 + lq * 4 + r) * DLP + nt * 16 + ln] = f2bf(acc[nt][r]);
    // same-wave write->read: compiler orders via lgkmcnt (LDS alias)
    const uint4* dp = (const uint4*)&Dl[(w * 16 + ln) * DLP + lq * 16];
    uint4 d0 = dp[0], d1 = dp[1];
    float r = 0.f;
    r = fmaf(bflo(d0.x), xv[0],  r); r = fmaf(bfhi(d0.x), xv[1],  r);
    r = fmaf(bflo(d0.y), xv[2],  r); r = fmaf(bfhi(d0.y), xv[3],  r);
    r = fmaf(bflo(d0.z), xv[4],  r); r = fmaf(bfhi(d0.z), xv[5],  r);
    r = fmaf(bflo(d0.w), xv[6],  r); r = fmaf(bfhi(d0.w), xv[7],  r);
    r = fmaf(bflo(d1.x), xv[8],  r); r = fmaf(bfhi(d1.x), xv[9],  r);
    r = fmaf(bflo(d1.y), xv[10], r); r = fmaf(bfhi(d1.y), xv[11], r);
    r = fmaf(bflo(d1.z), xv[12], r); r = fmaf(bfhi(d1.z), xv[13], r);
    r = fmaf(bflo(d1.w), xv[14], r); r = fmaf(bfhi(d1.w), xv[15], r);
    if (rowc < s1)
      y[((size_t)svc * CC + c) * 4 + lq] = r;
  }
}

// ============ lin_kernel: channel-mixing linear + pack ============
// grid 1024 (one node each) x 128 threads (n)
__global__ __launch_bounds__(128) void lin_kernel(
    const float* __restrict__ y, const float* __restrict__ w_lin,
    float* __restrict__ out) {
  int b = blockIdx.x;
  int n = threadIdx.x;
  const float4* yb4 = (const float4*)(y + (size_t)b * 512);
  float a0 = 0.f, a1 = 0.f, a2 = 0.f, a3 = 0.f;
  #pragma unroll 8
  for (int cc = 0; cc < CC; cc++) {
    float4 yv = yb4[cc];                        // uniform broadcast
    float wl0 = w_lin[(size_t)cc * CC + n];     // g=0
    float wl1 = w_lin[16384 + (size_t)cc * CC + n];
    a0 = fmaf(yv.x, wl0, a0);
    a1 = fmaf(yv.y, wl1, a1);
    a2 = fmaf(yv.z, wl1, a2);
    a3 = fmaf(yv.w, wl1, a3);
  }
  const float scale = 0.08838834764831845f;  // 1/sqrt(128)
  out[(size_t)b * 512 + n] = a0 * scale;
  out[(size_t)b * 512 + 128 + (size_t)n * 3 + 0] = a1 * scale;
  out[(size_t)b * 512 + 128 + (size_t)n * 3 + 1] = a2 * scale;
  out[(size_t)b * 512 + 128 + (size_t)n * 3 + 2] = a3 * scale;
}

extern "C" void kernel_launch(void* const* d_in, const int* in_sizes, int n_in,
                              void* d_out, int out_size, void* d_ws, size_t ws_size,
                              hipStream_t stream) {
  const float* node_feats = (const float*)d_in[0];
  const float* u3_0 = (const float*)d_in[1];
  const float* u3_1 = (const float*)d_in[2];
  const float* u2_0 = (const float*)d_in[3];
  const float* u2_1 = (const float*)d_in[4];
  const float* u1_0 = (const float*)d_in[5];
  const float* u1_1 = (const float*)d_in[6];
  const float* w3   = (const float*)d_in[7];
  const float* w2   = (const float*)d_in[8];
  const float* w1   = (const float*)d_in[9];
  const float* wlin = (const float*)d_in[10];
  const int* species = (const int*)d_in[11];
  float* out = (float*)d_out;

  char* ws = (char*)d_ws;
  ushort* W  = (ushort*)ws;                  // 512*18432*2 = 18,874,368 B
  float* yb  = (float*)(ws + 18874368);      //  2,097,152 B
  int* sorted = (int*)(ws + 20971520);       //      4,096 B
  int* seg    = (int*)(ws + 20975616);       //         32 B

  pre_kernel<<<1025, 256, 0, stream>>>(u3_0, u3_1, w3, u2_0, u2_1, u1_0, u1_1,
                                       w2, w1, species, W, sorted, seg);
  corr_kernel<<<1024, 256, 0, stream>>>(node_feats, W, sorted, seg, yb);
  lin_kernel<<<1024, 128, 0, stream>>>(yb, wlin, out);
}

// Round 8
// 123.722 us; speedup vs baseline: 1.5783x; 1.3662x over previous
//
#include <hip/hip_runtime.h>
#include <hip/hip_bf16.h>

#define SS 4
#define CC 128
#define WELEM 18432   // per-(s,c) W chunk, bf16 elems: 16384 main [n][jl] + 2048 tail (B-frag)
#define NK3 23
#define NK2 5
#define NK1 2
#define DLP 72        // Dl row stride (ushorts); 144 B = 16B-aligned rows

typedef unsigned int uint;
typedef unsigned short ushort;
typedef __attribute__((ext_vector_type(8))) short bf16x8;
typedef __attribute__((ext_vector_type(4))) float f32x4;

__device__ __forceinline__ float bflo(uint u){ return __uint_as_float(u << 16); }
__device__ __forceinline__ float bfhi(uint u){ return __uint_as_float(u & 0xffff0000u); }
__device__ __forceinline__ ushort f2bf(float f) {
  uint u = __float_as_uint(f);
  return (ushort)((u + 0x7fffu + ((u >> 16) & 1u)) >> 16);
}
__device__ __forceinline__ uint pk2(float a, float b) {
  __hip_bfloat162 h = __float22bfloat162_rn(make_float2(a, b));  // v_cvt_pk_bf16_f32
  return *(uint*)&h;
}

// ============ pre_kernel: fold3 (blocks 0..511) + fold21 (512..1023) + sort (1024) ============
__global__ __launch_bounds__(256) void pre_kernel(
    const float* __restrict__ u3_0, const float* __restrict__ u3_1,
    const float* __restrict__ w3,
    const float* __restrict__ u2_0, const float* __restrict__ u2_1,
    const float* __restrict__ u1_0, const float* __restrict__ u1_1,
    const float* __restrict__ w2,  const float* __restrict__ w1,
    const int* __restrict__ sp, ushort* __restrict__ W,
    int* __restrict__ sorted, int* __restrict__ seg) {
  __shared__ float smem[5888 + NK3 * 64];
  int bx = blockIdx.x;
  int tid = threadIdx.x;

  if (bx < 512) {
    // ---- fold3: W main, linear layout [s][c][n=o*16+i][jl], coalesced stores ----
    float* u3s = smem;            // 5888 floats
    float* w3s = smem + 5888;     // 23*64 floats
    int ch = bx & 1, i = (bx >> 1) & 15, o = (bx >> 5) & 3, s = bx >> 7;
    int g = (o > 0) ? 1 : 0, og = g ? (o - 1) : 0;
    const float* u3 = g ? u3_1 : u3_0;

    const float4* u3p = (const float4*)(u3 + (size_t)(og * 16 + i) * 5888);
    for (int d = tid; d < 1472; d += 256) {
      float4 v = u3p[d];
      u3s[4 * d] = v.x; u3s[4 * d + 1] = v.y; u3s[4 * d + 2] = v.z; u3s[4 * d + 3] = v.w;
    }
    for (int t = tid; t < NK3 * 64; t += 256) {
      int k = t >> 6, cp = t & 63;
      w3s[t] = w3[((size_t)(g * SS + s) * NK3 + k) * CC + ch * 64 + cp];
    }
    __syncthreads();

    float acc[64];
    #pragma unroll
    for (int q = 0; q < 64; q++) acc[q] = 0.f;
    int jl = tid;
    for (int k = 0; k < NK3; k++) {
      float u3v = u3s[jl * NK3 + k];
      const float4* wp = (const float4*)&w3s[k * 64];
      #pragma unroll
      for (int cq = 0; cq < 16; cq++) {
        float4 wv = wp[cq];
        acc[cq * 4 + 0] = fmaf(u3v, wv.x, acc[cq * 4 + 0]);
        acc[cq * 4 + 1] = fmaf(u3v, wv.y, acc[cq * 4 + 1]);
        acc[cq * 4 + 2] = fmaf(u3v, wv.z, acc[cq * 4 + 2]);
        acc[cq * 4 + 3] = fmaf(u3v, wv.w, acc[cq * 4 + 3]);
      }
    }
    int n = o * 16 + i;
    #pragma unroll
    for (int cp = 0; cp < 64; cp++) {
      W[(size_t)(s * CC + ch * 64 + cp) * WELEM + n * 256 + jl] = f2bf(acc[cp]);
    }
  } else if (bx < 1024) {
    // ---- fold21: W tail (k=256..287), stored directly in B-frag layout ----
    int b2 = bx - 512;
    int s = b2 >> 7, c = b2 & 127;
    int n = tid >> 2, lq = tid & 3;
    int o = n >> 4, i = n & 15;
    int g = (o > 0) ? 1 : 0, og = g ? (o - 1) : 0;
    const float* u2 = g ? u2_1 : u2_0;
    const float* u1 = g ? u1_1 : u1_0;

    float vals[8];
    #pragma unroll
    for (int t = 0; t < 8; t++) {
      int k = 256 + lq * 8 + t;
      float v = 0.f;
      if (k < 272) {
        int j = k - 256;
        #pragma unroll
        for (int k2 = 0; k2 < NK2; k2++)
          v = fmaf(u2[((size_t)(og * 16 + i) * 16 + j) * NK2 + k2],
                   w2[((size_t)(g * SS + s) * NK2 + k2) * CC + c], v);
      } else if (k == 272) {
        #pragma unroll
        for (int k2 = 0; k2 < NK1; k2++)
          v = fmaf(u1[(size_t)(og * 16 + i) * NK1 + k2],
                   w1[((size_t)(g * SS + s) * NK1 + k2) * CC + c], v);
      }
      vals[t] = v;
    }
    uint4 pk;
    pk.x = pk2(vals[0], vals[1]); pk.y = pk2(vals[2], vals[3]);
    pk.z = pk2(vals[4], vals[5]); pk.w = pk2(vals[6], vals[7]);
    size_t base = (size_t)(s * CC + c) * WELEM;
    size_t off = 16384 + ((size_t)o * 64 + lq * 16 + i) * 8;
    *(uint4*)(W + base + off) = pk;
  } else {
    // ---- sort nodes by species ----
    __shared__ int cnt[SS];
    __shared__ int basep[SS + 1];
    if (tid < SS) cnt[tid] = 0;
    __syncthreads();
    int mysp[4], mypos[4];
    #pragma unroll
    for (int q = 0; q < 4; q++) {
      int node = q * 256 + tid;
      int s = sp[node];
      mysp[q] = s;
      mypos[q] = atomicAdd(&cnt[s], 1);
    }
    __syncthreads();
    if (tid == 0) {
      basep[0] = 0;
      for (int q = 0; q < SS; q++) basep[q + 1] = basep[q] + cnt[q];
      for (int q = 0; q <= SS; q++) seg[q] = basep[q];
    }
    __syncthreads();
    #pragma unroll
    for (int q = 0; q < 4; q++)
      sorted[basep[mysp[q]] + mypos[q]] = q * 256 + tid;
  }
}

// ============ corr_kernel: MFMA symmetric contraction ============
// grid 1024 = h(2) x s(4) x c(128); 4 waves; wave w owns rows [w*16,w*16+16) of
// each 64-node slab; block h handles slabs h, h+2, ... of its (s,c) segment.
// x staged through wave-private LDS: one float4 per lane per slab (the rounds-5/7
// per-lane 4xfloat4 + 2x16-VGPR prefetch arrays caused ~100 MB/dispatch scratch
// round-trip — FETCH/WRITE ~100/104 MB vs clean 17.5/4 in round 3).
// All B fragments in LDS. Epilogue via per-wave bf16 LDS transpose (no shfl).
// No __syncthreads in the loop: xl/Dl are wave-private, same-wave LDS ordering.
__global__ __launch_bounds__(256, 2) void corr_kernel(
    const float* __restrict__ xg, const ushort* __restrict__ Wg,
    const int* __restrict__ sorted, const int* __restrict__ seg,
    float* __restrict__ y) {
  __shared__ uint4 Wl4[2304];                       // 36 KB: kt0..7 swizzled + kt8 tail
  __shared__ __align__(16) float xl[4][16][20];     // 5 KB, per-wave region
  __shared__ __align__(16) ushort Dl[4 * 16 * DLP]; // 9 KB, per-wave region
  int bx = blockIdx.x;
  int h = bx >> 9, s = (bx >> 7) & 3, c = bx & 127;
  int tid = threadIdx.x;
  int w = tid >> 6, lane = tid & 63;
  int lq = lane >> 4, ln = lane & 15;

  const uint4* wg = (const uint4*)(Wg + (size_t)(s * CC + c) * WELEM);

  // stage Wl: main kt0..7 (xor-swizzled), coalesced global reads
  for (int d = tid; d < 2048; d += 256) {
    int n = d >> 5, j = d & 31;            // j = kt*4 + lqj
    int kt = j >> 2, lqj = j & 3;
    Wl4[(kt * 4 + (n >> 4)) * 64 + ((lqj * 16 + (n & 15)) ^ kt)] = wg[d];
  }
  // tail kt8 (flat; already in B-frag order from fold21)
  Wl4[2048 + tid] = wg[2048 + tid];

  int s0 = seg[s], s1 = seg[s + 1];
  int nslab = (s1 - s0 + 63) >> 6;

  // pre-stage x for slab h: lane (lq,ln) loads chunk lq of row ln (16 B, no dup)
  int svcur = 0;
  if (h < nslab) {
    int row = s0 + h * 64 + w * 16 + ln;
    svcur = sorted[min(row, s1 - 1)];
    float4 v = *((const float4*)(xg + ((size_t)svcur * CC + c) * 16) + lq);
    *(float4*)(&xl[w][ln][lq * 4]) = v;
  }
  __syncthreads();  // Wl ready (the only barrier)

  for (int kslab = h; kslab < nslab; kslab += 2) {
    // own full row from wave-private LDS (4-way lq broadcast, 2-way ln alias: free)
    float xv[16];
    #pragma unroll
    for (int q = 0; q < 4; q++) {
      float4 v = *(const float4*)(&xl[w][ln][q * 4]);
      xv[q * 4] = v.x; xv[q * 4 + 1] = v.y; xv[q * 4 + 2] = v.z; xv[q * 4 + 3] = v.w;
    }
    int svc = svcur;
    int rowc = s0 + kslab * 64 + w * 16 + ln;
    // prefetch next slab x into 4 regs; LDS write deferred past the epilogue
    float4 xcn = make_float4(0.f, 0.f, 0.f, 0.f);
    int kn = kslab + 2;
    if (kn < nslab) {
      int row = s0 + kn * 64 + w * 16 + ln;
      svcur = sorted[min(row, s1 - 1)];
      xcn = *((const float4*)(xg + ((size_t)svcur * CC + c) * 16) + lq);
    }

    float xs8[8];
    #pragma unroll
    for (int t = 0; t < 8; t++) xs8[t] = (lq & 1) ? xv[8 + t] : xv[t];

    f32x4 acc[4];
    #pragma unroll
    for (int nt = 0; nt < 4; nt++) acc[nt] = (f32x4){0.f, 0.f, 0.f, 0.f};

    #pragma unroll
    for (int kt = 0; kt < 9; kt++) {
      uint4 av;
      if (kt < 8) {
        float xj = (lq & 2) ? xv[kt * 2 + 1] : xv[kt * 2];
        av.x = pk2(xj * xs8[0], xj * xs8[1]);
        av.y = pk2(xj * xs8[2], xj * xs8[3]);
        av.z = pk2(xj * xs8[4], xj * xs8[5]);
        av.w = pk2(xj * xs8[6], xj * xs8[7]);
      } else {
        av.x = pk2(xs8[0], xs8[1]);
        av.y = pk2(xs8[2], xs8[3]);
        av.z = pk2(xs8[4], xs8[5]);
        av.w = pk2(xs8[6], xs8[7]);
        if (lq == 2) av = make_uint4(0x3f80u, 0u, 0u, 0u);  // constant-1 column (k=272)
        if (lq == 3) av = make_uint4(0u, 0u, 0u, 0u);
      }
      bf16x8 a = *(bf16x8*)&av;
      #pragma unroll
      for (int nt = 0; nt < 4; nt++) {
        uint4 bv;
        if (kt < 8) {
          bv = Wl4[(kt * 4 + nt) * 64 + (lane ^ kt)];
        } else {
          bv = Wl4[2048 + nt * 64 + lane];
        }
        bf16x8 b = *(bf16x8*)&bv;
        acc[nt] = __builtin_amdgcn_mfma_f32_16x16x32_bf16(a, b, acc[nt], 0, 0, 0);
      }
    }

    // epilogue: per-wave LDS transpose of D (bf16), then lane (m=ln, o=lq)
    // reduces with its own xv (same row). C/D layout: row=lq*4+r, col=ln.
    #pragma unroll
    for (int nt = 0; nt < 4; nt++)
      #pragma unroll
      for (int r = 0; r < 4; r++)
        Dl[(w * 16 + lq * 4 + r) * DLP + nt * 16 + ln] = f2bf(acc[nt][r]);
    // same-wave write->read: compiler orders via lgkmcnt (LDS alias)
    const uint4* dp = (const uint4*)&Dl[(w * 16 + ln) * DLP + lq * 16];
    uint4 d0 = dp[0], d1 = dp[1];
    float r = 0.f;
    r = fmaf(bflo(d0.x), xv[0],  r); r = fmaf(bfhi(d0.x), xv[1],  r);
    r = fmaf(bflo(d0.y), xv[2],  r); r = fmaf(bfhi(d0.y), xv[3],  r);
    r = fmaf(bflo(d0.z), xv[4],  r); r = fmaf(bfhi(d0.z), xv[5],  r);
    r = fmaf(bflo(d0.w), xv[6],  r); r = fmaf(bfhi(d0.w), xv[7],  r);
    r = fmaf(bflo(d1.x), xv[8],  r); r = fmaf(bfhi(d1.x), xv[9],  r);
    r = fmaf(bflo(d1.y), xv[10], r); r = fmaf(bfhi(d1.y), xv[11], r);
    r = fmaf(bflo(d1.z), xv[12], r); r = fmaf(bfhi(d1.z), xv[13], r);
    r = fmaf(bflo(d1.w), xv[14], r); r = fmaf(bfhi(d1.w), xv[15], r);
    if (rowc < s1)
      y[((size_t)svc * CC + c) * 4 + lq] = r;

    // write prefetched x into wave-private xl (after xv/epilogue reads)
    if (kn < nslab)
      *(float4*)(&xl[w][ln][lq * 4]) = xcn;
  }
}

// ============ lin_kernel: channel-mixing linear + pack ============
// grid 1024 (one node each) x 128 threads (n)
__global__ __launch_bounds__(128) void lin_kernel(
    const float* __restrict__ y, const float* __restrict__ w_lin,
    float* __restrict__ out) {
  int b = blockIdx.x;
  int n = threadIdx.x;
  const float4* yb4 = (const float4*)(y + (size_t)b * 512);
  float a0 = 0.f, a1 = 0.f, a2 = 0.f, a3 = 0.f;
  #pragma unroll 8
  for (int cc = 0; cc < CC; cc++) {
    float4 yv = yb4[cc];                        // uniform broadcast
    float wl0 = w_lin[(size_t)cc * CC + n];     // g=0
    float wl1 = w_lin[16384 + (size_t)cc * CC + n];
    a0 = fmaf(yv.x, wl0, a0);
    a1 = fmaf(yv.y, wl1, a1);
    a2 = fmaf(yv.z, wl1, a2);
    a3 = fmaf(yv.w, wl1, a3);
  }
  const float scale = 0.08838834764831845f;  // 1/sqrt(128)
  out[(size_t)b * 512 + n] = a0 * scale;
  out[(size_t)b * 512 + 128 + (size_t)n * 3 + 0] = a1 * scale;
  out[(size_t)b * 512 + 128 + (size_t)n * 3 + 1] = a2 * scale;
  out[(size_t)b * 512 + 128 + (size_t)n * 3 + 2] = a3 * scale;
}

extern "C" void kernel_launch(void* const* d_in, const int* in_sizes, int n_in,
                              void* d_out, int out_size, void* d_ws, size_t ws_size,
                              hipStream_t stream) {
  const float* node_feats = (const float*)d_in[0];
  const float* u3_0 = (const float*)d_in[1];
  const float* u3_1 = (const float*)d_in[2];
  const float* u2_0 = (const float*)d_in[3];
  const float* u2_1 = (const float*)d_in[4];
  const float* u1_0 = (const float*)d_in[5];
  const float* u1_1 = (const float*)d_in[6];
  const float* w3   = (const float*)d_in[7];
  const float* w2   = (const float*)d_in[8];
  const float* w1   = (const float*)d_in[9];
  const float* wlin = (const float*)d_in[10];
  const int* species = (const int*)d_in[11];
  float* out = (float*)d_out;

  char* ws = (char*)d_ws;
  ushort* W  = (ushort*)ws;                  // 512*18432*2 = 18,874,368 B
  float* yb  = (float*)(ws + 18874368);      //  2,097,152 B
  int* sorted = (int*)(ws + 20971520);       //      4,096 B
  int* seg    = (int*)(ws + 20975616);       //         32 B

  pre_kernel<<<1025, 256, 0, stream>>>(u3_0, u3_1, w3, u2_0, u2_1, u1_0, u1_1,
                                       w2, w1, species, W, sorted, seg);
  corr_kernel<<<1024, 256, 0, stream>>>(node_feats, W, sorted, seg, yb);
  lin_kernel<<<1024, 128, 0, stream>>>(yb, wlin, out);
}